// Round 7
// baseline (223.053 us; speedup 1.0000x reference)
//
#include <hip/hip_runtime.h>
#include <hip/hip_fp16.h>

#define D 96
#define D4 24

static inline size_t alignup(size_t x) { return (x + 255) & ~size_t(255); }

__device__ inline float4 f4fma(float s, float4 a, float4 acc) {
    acc.x = fmaf(s, a.x, acc.x);
    acc.y = fmaf(s, a.y, acc.y);
    acc.z = fmaf(s, a.z, acc.z);
    acc.w = fmaf(s, a.w, acc.w);
    return acc;
}

// gather one fp16 row chunk (8B = 4 halves) and FMA into acc
__device__ inline float4 h4fma(const uint2* __restrict__ XH, int s, int t, float w, float4 acc) {
    uint2 rv = XH[(size_t)s * D4 + t];
    __half2 ha = *reinterpret_cast<__half2*>(&rv.x);
    __half2 hb = *reinterpret_cast<__half2*>(&rv.y);
    float2 f0 = __half22float2(ha);
    float2 f1 = __half22float2(hb);
    acc.x = fmaf(w, f0.x, acc.x);
    acc.y = fmaf(w, f0.y, acc.y);
    acc.z = fmaf(w, f1.x, acc.z);
    acc.w = fmaf(w, f1.y, acc.w);
    return acc;
}

// deg = 0, head = -1 (vectorized)
__global__ void init_kernel(int4* __restrict__ deg4, int4* __restrict__ head4, int n4) {
    int i = blockIdx.x * blockDim.x + threadIdx.x;
    if (i < n4) {
        deg4[i] = make_int4(0, 0, 0, 0);
        head4[i] = make_int4(-1, -1, -1, -1);
    }
}

// Per-node linked lists: next[e] written at position e (coalesced);
// head/deg are 200KB L2-resident atomic targets. Replaces count+scatter-fill.
__global__ void build_lists_kernel(const int* __restrict__ dst, int E,
                                   int* __restrict__ deg, int* __restrict__ head,
                                   int* __restrict__ next) {
    int e = blockIdx.x * blockDim.x + threadIdx.x;
    if (e < E) {
        int d = dst[e];
        atomicAdd(&deg[d], 1);
        next[e] = atomicExch(&head[d], e);
    }
}

// Phase 1: per-block exclusive scan of deg -> rowptr (local), block totals -> bsum.
// Fused: dinv[i] = rsqrt(deg[i]+1).
__global__ __launch_bounds__(1024) void scan_blocks_kernel(const int* __restrict__ deg,
                                                           int* __restrict__ rowptr,
                                                           float* __restrict__ dinv,
                                                           int* __restrict__ bsum, int n) {
    __shared__ int wsum[16];
    const int i = blockIdx.x * 1024 + threadIdx.x;
    const int lane = threadIdx.x & 63;
    const int wid  = threadIdx.x >> 6;
    int v = (i < n) ? deg[i] : 0;
    if (i < n) dinv[i] = rsqrtf((float)(v + 1));  // +1 = self-loop
    int sc = v;
    #pragma unroll
    for (int off = 1; off < 64; off <<= 1) {
        int t = __shfl_up(sc, off);
        if (lane >= off) sc += t;
    }
    if (lane == 63) wsum[wid] = sc;
    __syncthreads();
    int wprefix = 0;
    #pragma unroll
    for (int k = 0; k < 16; ++k)
        if (k < wid) wprefix += wsum[k];
    if (i < n) rowptr[i] = wprefix + (sc - v);
    if (threadIdx.x == 1023) bsum[blockIdx.x] = wprefix + sc;
}

// Phase 2: one block scans block sums (nb <= 1024).
__global__ __launch_bounds__(1024) void scan_partials_kernel(const int* __restrict__ bsum,
                                                             int* __restrict__ boff,
                                                             int* __restrict__ rowptr,
                                                             int nb, int n) {
    __shared__ int wsum[16];
    const int lane = threadIdx.x & 63;
    const int wid  = threadIdx.x >> 6;
    int v = ((int)threadIdx.x < nb) ? bsum[threadIdx.x] : 0;
    int sc = v;
    #pragma unroll
    for (int off = 1; off < 64; off <<= 1) {
        int t = __shfl_up(sc, off);
        if (lane >= off) sc += t;
    }
    if (lane == 63) wsum[wid] = sc;
    __syncthreads();
    int wprefix = 0;
    #pragma unroll
    for (int k = 0; k < 16; ++k)
        if (k < wid) wprefix += wsum[k];
    if ((int)threadIdx.x < nb) boff[threadIdx.x] = wprefix + (sc - v);
    if ((int)threadIdx.x == nb - 1) rowptr[n] = wprefix + sc;
}

// Phase 3: globalize rowptr.
__global__ __launch_bounds__(1024) void scan_add_kernel(int* __restrict__ rowptr,
                                                        const int* __restrict__ boff, int n) {
    int i = blockIdx.x * 1024 + threadIdx.x;
    if (i < n) rowptr[i] += boff[blockIdx.x];
}

// Walk each node's linked list; write its CSR segment sequentially (full-line writes).
__global__ void convert_kernel(const int* __restrict__ src, const int* __restrict__ head,
                               const int* __restrict__ next, const int* __restrict__ rowptr,
                               const float* __restrict__ dinv, int2* __restrict__ csr, int n) {
    int i = blockIdx.x * blockDim.x + threadIdx.x;
    if (i >= n) return;
    int p = rowptr[i];
    int e = head[i];
    while (e >= 0) {
        int nx = next[e];          // issue hop load first
        int s = src[e];
        csr[p++] = make_int2(s, __float_as_int(dinv[s]));
        e = nx;
    }
}

// Y[n,96](fp16) = X[n,96](fp32) @ W[96,96](fp32).
// block (24,8)=192 threads, 64 rows/block; thread computes 8 rows x 4 cols.
__global__ __launch_bounds__(192) void matmul_kernel(const float* __restrict__ X,
                                                     const float* __restrict__ W,
                                                     uint2* __restrict__ Y, int n) {
    __shared__ float XsT[96 * 64];
    const int t = threadIdx.x;        // 0..23 col-group
    const int y = threadIdx.y;        // 0..7 row-group
    const int tid = y * 24 + t;
    const int row0 = blockIdx.x * 64;
    const float4* X4 = (const float4*)X;

    for (int i = tid; i < 64 * 24; i += 192) {
        int r = i / 24, c4 = i % 24;
        float4 v = make_float4(0.f, 0.f, 0.f, 0.f);
        if (row0 + r < n) v = X4[(size_t)(row0 + r) * D4 + c4];
        int rs = r ^ ((c4 & 15) << 2);
        XsT[(c4 * 4 + 0) * 64 + rs] = v.x;
        XsT[(c4 * 4 + 1) * 64 + rs] = v.y;
        XsT[(c4 * 4 + 2) * 64 + rs] = v.z;
        XsT[(c4 * 4 + 3) * 64 + rs] = v.w;
    }
    __syncthreads();

    const float4* W4 = (const float4*)W;
    float4 acc[8];
    #pragma unroll
    for (int r = 0; r < 8; ++r) acc[r] = make_float4(0.f, 0.f, 0.f, 0.f);
    const int rbase = y * 8;

    #pragma unroll 8
    for (int k = 0; k < 96; ++k) {
        float4 w = W4[k * D4 + t];
        int base0 = (rbase ^ (((k >> 2) & 15) << 2));
        float4 xa = *(const float4*)&XsT[k * 64 + base0];
        float4 xb = *(const float4*)&XsT[k * 64 + (base0 ^ 4)];
        acc[0] = f4fma(xa.x, w, acc[0]);
        acc[1] = f4fma(xa.y, w, acc[1]);
        acc[2] = f4fma(xa.z, w, acc[2]);
        acc[3] = f4fma(xa.w, w, acc[3]);
        acc[4] = f4fma(xb.x, w, acc[4]);
        acc[5] = f4fma(xb.y, w, acc[5]);
        acc[6] = f4fma(xb.z, w, acc[6]);
        acc[7] = f4fma(xb.w, w, acc[7]);
    }

    #pragma unroll
    for (int r = 0; r < 8; ++r) {
        int row = row0 + rbase + r;
        if (row < n) {
            __half2 ha = __float22half2_rn(make_float2(acc[r].x, acc[r].y));
            __half2 hb = __float22half2_rn(make_float2(acc[r].z, acc[r].w));
            uint2 st;
            st.x = *reinterpret_cast<unsigned int*>(&ha);
            st.y = *reinterpret_cast<unsigned int*>(&hb);
            Y[(size_t)row * D4 + t] = st;
        }
    }
}

// out[i,:] = prelu( dinv[i]*sum_e w_e*XW[src_e,:] + dinv[i]^2*XW[i,:] + b ), XW in fp16.
// block (24,16): 24 threads/node, 16 nodes/block; edge loop unrolled x8.
__global__ __launch_bounds__(384) void aggregate_kernel(const uint2* __restrict__ XH,
                                                        const int2* __restrict__ csr,
                                                        const int* __restrict__ rowptr,
                                                        const float* __restrict__ dinv,
                                                        const float4* __restrict__ b4,
                                                        const float4* __restrict__ pa4,
                                                        float4* __restrict__ out4, int n) {
    const int i = blockIdx.x * 16 + threadIdx.y;
    const int t = threadIdx.x;  // 0..23
    if (i >= n) return;
    const int beg = rowptr[i], end = rowptr[i + 1];
    float4 acc = make_float4(0.f, 0.f, 0.f, 0.f);
    int p = beg;
    for (; p + 8 <= end; p += 8) {
        int2 e0 = csr[p + 0];
        int2 e1 = csr[p + 1];
        int2 e2 = csr[p + 2];
        int2 e3 = csr[p + 3];
        int2 e4 = csr[p + 4];
        int2 e5 = csr[p + 5];
        int2 e6 = csr[p + 6];
        int2 e7 = csr[p + 7];
        acc = h4fma(XH, e0.x, t, __int_as_float(e0.y), acc);
        acc = h4fma(XH, e1.x, t, __int_as_float(e1.y), acc);
        acc = h4fma(XH, e2.x, t, __int_as_float(e2.y), acc);
        acc = h4fma(XH, e3.x, t, __int_as_float(e3.y), acc);
        acc = h4fma(XH, e4.x, t, __int_as_float(e4.y), acc);
        acc = h4fma(XH, e5.x, t, __int_as_float(e5.y), acc);
        acc = h4fma(XH, e6.x, t, __int_as_float(e6.y), acc);
        acc = h4fma(XH, e7.x, t, __int_as_float(e7.y), acc);
    }
    if (p + 4 <= end) {
        int2 e0 = csr[p + 0];
        int2 e1 = csr[p + 1];
        int2 e2 = csr[p + 2];
        int2 e3 = csr[p + 3];
        acc = h4fma(XH, e0.x, t, __int_as_float(e0.y), acc);
        acc = h4fma(XH, e1.x, t, __int_as_float(e1.y), acc);
        acc = h4fma(XH, e2.x, t, __int_as_float(e2.y), acc);
        acc = h4fma(XH, e3.x, t, __int_as_float(e3.y), acc);
        p += 4;
    }
    for (; p < end; ++p) {
        int2 e = csr[p];
        acc = h4fma(XH, e.x, t, __int_as_float(e.y), acc);
    }
    const float di = dinv[i];
    float4 self = make_float4(0.f, 0.f, 0.f, 0.f);
    self = h4fma(XH, i, t, 1.f, self);
    float4 b = b4[t], a = pa4[t];
    float4 v;
    v.x = fmaf(di, acc.x, di * di * self.x) + b.x;
    v.y = fmaf(di, acc.y, di * di * self.y) + b.y;
    v.z = fmaf(di, acc.z, di * di * self.z) + b.z;
    v.w = fmaf(di, acc.w, di * di * self.w) + b.w;
    v.x = v.x > 0.f ? v.x : a.x * v.x;
    v.y = v.y > 0.f ? v.y : a.y * v.y;
    v.z = v.z > 0.f ? v.z : a.z * v.z;
    v.w = v.w > 0.f ? v.w : a.w * v.w;
    out4[(size_t)i * D4 + t] = v;
}

extern "C" void kernel_launch(void* const* d_in, const int* in_sizes, int n_in,
                              void* d_out, int out_size, void* d_ws, size_t ws_size,
                              hipStream_t stream) {
    const float* x   = (const float*)d_in[0];
    const int*   ei  = (const int*)d_in[1];
    const float* W1  = (const float*)d_in[2];
    const float* b1  = (const float*)d_in[3];
    const float* W2  = (const float*)d_in[4];
    const float* b2  = (const float*)d_in[5];
    const float* pa  = (const float*)d_in[6];
    const int n = in_sizes[0] / D;
    const int E = in_sizes[1] / 2;
    const int* srcp = ei;
    const int* dstp = ei + E;

    char* w = (char*)d_ws;
    int*   deg    = (int*)w;   w += alignup((size_t)n * 4);
    int*   head   = (int*)w;   w += alignup((size_t)n * 4);
    int*   next   = (int*)w;   w += alignup((size_t)E * 4);
    float* dinv   = (float*)w; w += alignup((size_t)n * 4);
    int*   rowptr = (int*)w;   w += alignup((size_t)(n + 1) * 4);
    int*   bsum   = (int*)w;   w += alignup(1024 * 4);
    int*   boff   = (int*)w;   w += alignup(1024 * 4);
    int2*  csr    = (int2*)w;  w += alignup((size_t)E * 8);
    uint2* xw     = (uint2*)w; w += alignup((size_t)n * D * 2);  // fp16 rows
    float* out    = (float*)d_out;

    const int tb = 256;
    const int nb = (n + 1023) / 1024;
    const int n4 = (n + 3) / 4;
    init_kernel<<<(n4 + tb - 1) / tb, tb, 0, stream>>>((int4*)deg, (int4*)head, n4);
    build_lists_kernel<<<(E + tb - 1) / tb, tb, 0, stream>>>(dstp, E, deg, head, next);
    scan_blocks_kernel<<<nb, 1024, 0, stream>>>(deg, rowptr, dinv, bsum, n);
    scan_partials_kernel<<<1, 1024, 0, stream>>>(bsum, boff, rowptr, nb, n);
    scan_add_kernel<<<nb, 1024, 0, stream>>>(rowptr, boff, n);
    convert_kernel<<<(n + tb - 1) / tb, tb, 0, stream>>>(srcp, head, next, rowptr, dinv, csr, n);

    dim3 mblk(24, 8);
    const int mgrid = (n + 63) / 64;
    dim3 ablk(24, 16);
    const int agrid = (n + 15) / 16;

    matmul_kernel<<<mgrid, mblk, 0, stream>>>(x, W1, xw, n);
    aggregate_kernel<<<agrid, ablk, 0, stream>>>(xw, csr, rowptr, dinv,
                                                 (const float4*)b1, (const float4*)pa, (float4*)out, n);
    matmul_kernel<<<mgrid, mblk, 0, stream>>>(out, W2, xw, n);
    aggregate_kernel<<<agrid, ablk, 0, stream>>>(xw, csr, rowptr, dinv,
                                                 (const float4*)b2, (const float4*)pa, (float4*)out, n);
}

// Round 8
// 145.999 us; speedup vs baseline: 1.5278x; 1.5278x over previous
//
#include <hip/hip_runtime.h>
#include <hip/hip_fp16.h>

#define D 96
#define D4 24
#define MAXBINS 256   // buckets of 256 nodes; n <= 65536

static inline size_t alignup(size_t x) { return (x + 255) & ~size_t(255); }

__device__ inline float4 f4fma(float s, float4 a, float4 acc) {
    acc.x = fmaf(s, a.x, acc.x);
    acc.y = fmaf(s, a.y, acc.y);
    acc.z = fmaf(s, a.z, acc.z);
    acc.w = fmaf(s, a.w, acc.w);
    return acc;
}

// gather one fp16 row chunk (8B = 4 halves) and FMA into acc
__device__ inline float4 h4fma(const uint2* __restrict__ XH, int s, int t, float w, float4 acc) {
    uint2 rv = XH[(size_t)s * D4 + t];
    __half2 ha = *reinterpret_cast<__half2*>(&rv.x);
    __half2 hb = *reinterpret_cast<__half2*>(&rv.y);
    float2 f0 = __half22float2(ha);
    float2 f1 = __half22float2(hb);
    acc.x = fmaf(w, f0.x, acc.x);
    acc.y = fmaf(w, f0.y, acc.y);
    acc.z = fmaf(w, f1.x, acc.z);
    acc.w = fmaf(w, f1.y, acc.w);
    return acc;
}

// ---- bucket-sort pipeline (no per-edge global atomics) ----

// Per-block LDS histogram of dst>>8; bhist is block-major [b*nbins + bin] (coalesced).
__global__ __launch_bounds__(1024) void hist_kernel(const int* __restrict__ dst, int E,
                                                    int* __restrict__ bhist, int nbins) {
    __shared__ int h[MAXBINS];
    const int tid = threadIdx.x;
    if (tid < nbins) h[tid] = 0;
    __syncthreads();
    int e = blockIdx.x * 1024 + tid;
    if (e < E) atomicAdd(&h[dst[e] >> 8], 1);
    __syncthreads();
    if (tid < nbins) bhist[blockIdx.x * nbins + tid] = h[tid];
}

// Generic hierarchical exclusive scan, phase 1. Reads bhist PERMUTED into bin-major
// order: scan index i <-> (bin = i/nblk, b = i%nblk), element = bhist[b*nbins+bin].
__global__ __launch_bounds__(1024) void scan1_kernel(const int* __restrict__ bhist,
                                                     int* __restrict__ boffs,
                                                     int* __restrict__ bsum,
                                                     int m, int nblk, int nbins) {
    __shared__ int wsum[16];
    const int i = blockIdx.x * 1024 + threadIdx.x;
    const int lane = threadIdx.x & 63;
    const int wid  = threadIdx.x >> 6;
    int v = 0;
    if (i < m) {
        int b = i % nblk, bin = i / nblk;
        v = bhist[b * nbins + bin];
    }
    int sc = v;
    #pragma unroll
    for (int off = 1; off < 64; off <<= 1) {
        int t = __shfl_up(sc, off);
        if (lane >= off) sc += t;
    }
    if (lane == 63) wsum[wid] = sc;
    __syncthreads();
    int wprefix = 0;
    #pragma unroll
    for (int k = 0; k < 16; ++k)
        if (k < wid) wprefix += wsum[k];
    if (i < m) boffs[i] = wprefix + (sc - v);
    if (threadIdx.x == 1023) bsum[blockIdx.x] = wprefix + sc;
}

// Phase 2: one block scans block sums (nb <= 1024).
__global__ __launch_bounds__(1024) void scan2_kernel(const int* __restrict__ bsum,
                                                     int* __restrict__ boff, int nb) {
    __shared__ int wsum[16];
    const int lane = threadIdx.x & 63;
    const int wid  = threadIdx.x >> 6;
    int v = ((int)threadIdx.x < nb) ? bsum[threadIdx.x] : 0;
    int sc = v;
    #pragma unroll
    for (int off = 1; off < 64; off <<= 1) {
        int t = __shfl_up(sc, off);
        if (lane >= off) sc += t;
    }
    if (lane == 63) wsum[wid] = sc;
    __syncthreads();
    int wprefix = 0;
    #pragma unroll
    for (int k = 0; k < 16; ++k)
        if (k < wid) wprefix += wsum[k];
    if ((int)threadIdx.x < nb) boff[threadIdx.x] = wprefix + (sc - v);
}

// Phase 3: globalize.
__global__ __launch_bounds__(1024) void scan3_kernel(int* __restrict__ boffs,
                                                     const int* __restrict__ boff, int m) {
    int i = blockIdx.x * 1024 + threadIdx.x;
    if (i < m) boffs[i] += boff[blockIdx.x];
}

// Distribute edges grouped by bucket: LDS ranking only; contiguous chunk writes.
__global__ __launch_bounds__(1024) void dist_kernel(const int* __restrict__ src,
                                                    const int* __restrict__ dst, int E,
                                                    const int* __restrict__ boffs,
                                                    int nblk, int nbins,
                                                    int2* __restrict__ ebuf) {
    __shared__ int h[MAXBINS];
    __shared__ int base[MAXBINS];
    const int tid = threadIdx.x;
    if (tid < nbins) h[tid] = 0;
    __syncthreads();
    int e = blockIdx.x * 1024 + tid;
    int s = 0, d = 0, bin = 0, rank = 0;
    bool valid = e < E;
    if (valid) {
        s = src[e]; d = dst[e];
        bin = d >> 8;
        rank = atomicAdd(&h[bin], 1);
    }
    __syncthreads();
    if (tid < nbins) base[tid] = boffs[tid * nblk + blockIdx.x];
    __syncthreads();
    if (valid) ebuf[base[bin] + rank] = make_int2(s, d);
}

// One workgroup per bucket (256 nodes): count low-8 dst in LDS, prefix-scan,
// write dinv + rowptr (bucket base + local prefix). Deletes the global node scan.
__global__ __launch_bounds__(256) void bucketA_kernel(const int2* __restrict__ ebuf,
                                                      const int* __restrict__ boffs,
                                                      int nblk, int nbins,
                                                      float* __restrict__ dinv,
                                                      int* __restrict__ rowptr,
                                                      int n, int E) {
    __shared__ int cnt[256];
    __shared__ int wsum[4];
    const int k = blockIdx.x;
    const int tid = threadIdx.x;
    const int bstart = boffs[k * nblk];
    const int bend = (k + 1 < nbins) ? boffs[(k + 1) * nblk] : E;
    cnt[tid] = 0;
    __syncthreads();
    for (int e = bstart + tid; e < bend; e += 256)
        atomicAdd(&cnt[ebuf[e].y & 255], 1);
    __syncthreads();
    int v = cnt[tid];
    const int lane = tid & 63, wid = tid >> 6;
    int sc = v;
    #pragma unroll
    for (int off = 1; off < 64; off <<= 1) {
        int t = __shfl_up(sc, off);
        if (lane >= off) sc += t;
    }
    if (lane == 63) wsum[wid] = sc;
    __syncthreads();
    int wprefix = 0;
    #pragma unroll
    for (int w = 0; w < 4; ++w)
        if (w < wid) wprefix += wsum[w];
    int node = k * 256 + tid;
    if (node < n) {
        dinv[node] = rsqrtf((float)(v + 1));      // +1 = self-loop
        rowptr[node] = bstart + wprefix + (sc - v);
    }
    if (k == nbins - 1 && tid == 0) rowptr[n] = E;
}

// Fill CSR: rank via LDS atomic; all writes land in this bucket's contiguous
// region (same workgroup, same L2) -> full-line writebacks.
__global__ __launch_bounds__(256) void bucketB_kernel(const int2* __restrict__ ebuf,
                                                      const int* __restrict__ boffs,
                                                      int nblk, int nbins,
                                                      const int* __restrict__ rowptr,
                                                      const float* __restrict__ dinv,
                                                      int2* __restrict__ csr, int E) {
    __shared__ int cnt[256];
    const int k = blockIdx.x;
    const int tid = threadIdx.x;
    const int bstart = boffs[k * nblk];
    const int bend = (k + 1 < nbins) ? boffs[(k + 1) * nblk] : E;
    cnt[tid] = 0;
    __syncthreads();
    for (int e = bstart + tid; e < bend; e += 256) {
        int2 ed = ebuf[e];
        int rank = atomicAdd(&cnt[ed.y & 255], 1);
        csr[rowptr[ed.y] + rank] = make_int2(ed.x, __float_as_int(dinv[ed.x]));
    }
}

// ---- dense transform + aggregation (unchanged) ----

// Y[n,96](fp16) = X[n,96](fp32) @ W[96,96](fp32).
__global__ __launch_bounds__(192) void matmul_kernel(const float* __restrict__ X,
                                                     const float* __restrict__ W,
                                                     uint2* __restrict__ Y, int n) {
    __shared__ float XsT[96 * 64];
    const int t = threadIdx.x;        // 0..23 col-group
    const int y = threadIdx.y;        // 0..7 row-group
    const int tid = y * 24 + t;
    const int row0 = blockIdx.x * 64;
    const float4* X4 = (const float4*)X;

    for (int i = tid; i < 64 * 24; i += 192) {
        int r = i / 24, c4 = i % 24;
        float4 v = make_float4(0.f, 0.f, 0.f, 0.f);
        if (row0 + r < n) v = X4[(size_t)(row0 + r) * D4 + c4];
        int rs = r ^ ((c4 & 15) << 2);
        XsT[(c4 * 4 + 0) * 64 + rs] = v.x;
        XsT[(c4 * 4 + 1) * 64 + rs] = v.y;
        XsT[(c4 * 4 + 2) * 64 + rs] = v.z;
        XsT[(c4 * 4 + 3) * 64 + rs] = v.w;
    }
    __syncthreads();

    const float4* W4 = (const float4*)W;
    float4 acc[8];
    #pragma unroll
    for (int r = 0; r < 8; ++r) acc[r] = make_float4(0.f, 0.f, 0.f, 0.f);
    const int rbase = y * 8;

    #pragma unroll 8
    for (int k = 0; k < 96; ++k) {
        float4 w = W4[k * D4 + t];
        int base0 = (rbase ^ (((k >> 2) & 15) << 2));
        float4 xa = *(const float4*)&XsT[k * 64 + base0];
        float4 xb = *(const float4*)&XsT[k * 64 + (base0 ^ 4)];
        acc[0] = f4fma(xa.x, w, acc[0]);
        acc[1] = f4fma(xa.y, w, acc[1]);
        acc[2] = f4fma(xa.z, w, acc[2]);
        acc[3] = f4fma(xa.w, w, acc[3]);
        acc[4] = f4fma(xb.x, w, acc[4]);
        acc[5] = f4fma(xb.y, w, acc[5]);
        acc[6] = f4fma(xb.z, w, acc[6]);
        acc[7] = f4fma(xb.w, w, acc[7]);
    }

    #pragma unroll
    for (int r = 0; r < 8; ++r) {
        int row = row0 + rbase + r;
        if (row < n) {
            __half2 ha = __float22half2_rn(make_float2(acc[r].x, acc[r].y));
            __half2 hb = __float22half2_rn(make_float2(acc[r].z, acc[r].w));
            uint2 st;
            st.x = *reinterpret_cast<unsigned int*>(&ha);
            st.y = *reinterpret_cast<unsigned int*>(&hb);
            Y[(size_t)row * D4 + t] = st;
        }
    }
}

// out[i,:] = prelu( dinv[i]*sum_e w_e*XW[src_e,:] + dinv[i]^2*XW[i,:] + b ), XW fp16.
__global__ __launch_bounds__(384) void aggregate_kernel(const uint2* __restrict__ XH,
                                                        const int2* __restrict__ csr,
                                                        const int* __restrict__ rowptr,
                                                        const float* __restrict__ dinv,
                                                        const float4* __restrict__ b4,
                                                        const float4* __restrict__ pa4,
                                                        float4* __restrict__ out4, int n) {
    const int i = blockIdx.x * 16 + threadIdx.y;
    const int t = threadIdx.x;  // 0..23
    if (i >= n) return;
    const int beg = rowptr[i], end = rowptr[i + 1];
    float4 acc = make_float4(0.f, 0.f, 0.f, 0.f);
    int p = beg;
    for (; p + 8 <= end; p += 8) {
        int2 e0 = csr[p + 0];
        int2 e1 = csr[p + 1];
        int2 e2 = csr[p + 2];
        int2 e3 = csr[p + 3];
        int2 e4 = csr[p + 4];
        int2 e5 = csr[p + 5];
        int2 e6 = csr[p + 6];
        int2 e7 = csr[p + 7];
        acc = h4fma(XH, e0.x, t, __int_as_float(e0.y), acc);
        acc = h4fma(XH, e1.x, t, __int_as_float(e1.y), acc);
        acc = h4fma(XH, e2.x, t, __int_as_float(e2.y), acc);
        acc = h4fma(XH, e3.x, t, __int_as_float(e3.y), acc);
        acc = h4fma(XH, e4.x, t, __int_as_float(e4.y), acc);
        acc = h4fma(XH, e5.x, t, __int_as_float(e5.y), acc);
        acc = h4fma(XH, e6.x, t, __int_as_float(e6.y), acc);
        acc = h4fma(XH, e7.x, t, __int_as_float(e7.y), acc);
    }
    if (p + 4 <= end) {
        int2 e0 = csr[p + 0];
        int2 e1 = csr[p + 1];
        int2 e2 = csr[p + 2];
        int2 e3 = csr[p + 3];
        acc = h4fma(XH, e0.x, t, __int_as_float(e0.y), acc);
        acc = h4fma(XH, e1.x, t, __int_as_float(e1.y), acc);
        acc = h4fma(XH, e2.x, t, __int_as_float(e2.y), acc);
        acc = h4fma(XH, e3.x, t, __int_as_float(e3.y), acc);
        p += 4;
    }
    for (; p < end; ++p) {
        int2 e = csr[p];
        acc = h4fma(XH, e.x, t, __int_as_float(e.y), acc);
    }
    const float di = dinv[i];
    float4 self = make_float4(0.f, 0.f, 0.f, 0.f);
    self = h4fma(XH, i, t, 1.f, self);
    float4 b = b4[t], a = pa4[t];
    float4 v;
    v.x = fmaf(di, acc.x, di * di * self.x) + b.x;
    v.y = fmaf(di, acc.y, di * di * self.y) + b.y;
    v.z = fmaf(di, acc.z, di * di * self.z) + b.z;
    v.w = fmaf(di, acc.w, di * di * self.w) + b.w;
    v.x = v.x > 0.f ? v.x : a.x * v.x;
    v.y = v.y > 0.f ? v.y : a.y * v.y;
    v.z = v.z > 0.f ? v.z : a.z * v.z;
    v.w = v.w > 0.f ? v.w : a.w * v.w;
    out4[(size_t)i * D4 + t] = v;
}

extern "C" void kernel_launch(void* const* d_in, const int* in_sizes, int n_in,
                              void* d_out, int out_size, void* d_ws, size_t ws_size,
                              hipStream_t stream) {
    const float* x   = (const float*)d_in[0];
    const int*   ei  = (const int*)d_in[1];
    const float* W1  = (const float*)d_in[2];
    const float* b1  = (const float*)d_in[3];
    const float* W2  = (const float*)d_in[4];
    const float* b2  = (const float*)d_in[5];
    const float* pa  = (const float*)d_in[6];
    const int n = in_sizes[0] / D;
    const int E = in_sizes[1] / 2;
    const int* srcp = ei;
    const int* dstp = ei + E;

    const int nbins  = (n + 255) / 256;           // 196
    const int nblk_e = (E + 1023) / 1024;         // 782
    const int m      = nbins * nblk_e;            // 153272
    const int nbscan = (m + 1023) / 1024;         // 150

    char* w = (char*)d_ws;
    int*   bhist  = (int*)w;   w += alignup((size_t)m * 4);
    int*   boffs  = (int*)w;   w += alignup((size_t)m * 4);
    int*   bsum   = (int*)w;   w += alignup(1024 * 4);
    int*   bboff  = (int*)w;   w += alignup(1024 * 4);
    float* dinv   = (float*)w; w += alignup((size_t)n * 4);
    int*   rowptr = (int*)w;   w += alignup((size_t)(n + 1) * 4);
    int2*  ebuf   = (int2*)w;  w += alignup((size_t)E * 8);
    int2*  csr    = (int2*)w;  w += alignup((size_t)E * 8);
    uint2* xw     = (uint2*)w; w += alignup((size_t)n * D * 2);  // fp16 rows
    float* out    = (float*)d_out;

    hist_kernel<<<nblk_e, 1024, 0, stream>>>(dstp, E, bhist, nbins);
    scan1_kernel<<<nbscan, 1024, 0, stream>>>(bhist, boffs, bsum, m, nblk_e, nbins);
    scan2_kernel<<<1, 1024, 0, stream>>>(bsum, bboff, nbscan);
    scan3_kernel<<<nbscan, 1024, 0, stream>>>(boffs, bboff, m);
    dist_kernel<<<nblk_e, 1024, 0, stream>>>(srcp, dstp, E, boffs, nblk_e, nbins, ebuf);
    bucketA_kernel<<<nbins, 256, 0, stream>>>(ebuf, boffs, nblk_e, nbins, dinv, rowptr, n, E);
    bucketB_kernel<<<nbins, 256, 0, stream>>>(ebuf, boffs, nblk_e, nbins, rowptr, dinv, csr, E);

    dim3 mblk(24, 8);
    const int mgrid = (n + 63) / 64;
    dim3 ablk(24, 16);
    const int agrid = (n + 15) / 16;

    matmul_kernel<<<mgrid, mblk, 0, stream>>>(x, W1, xw, n);
    aggregate_kernel<<<agrid, ablk, 0, stream>>>(xw, csr, rowptr, dinv,
                                                 (const float4*)b1, (const float4*)pa, (float4*)out, n);
    matmul_kernel<<<mgrid, mblk, 0, stream>>>(out, W2, xw, n);
    aggregate_kernel<<<agrid, ablk, 0, stream>>>(xw, csr, rowptr, dinv,
                                                 (const float4*)b2, (const float4*)pa, (float4*)out, n);
}